// Round 3
// baseline (975.066 us; speedup 1.0000x reference)
//
#include <hip/hip_runtime.h>
#include <hip/hip_bf16.h>

#define NODE_DIM 256
#define COND_DIM 512
#define OUT_DIM  128
#define HID      64
#define LN_EPS   1e-5f

// dst-bin partition: windows of 256 nodes -> nbin = ceil(N/256) (=391 for N=100000)
#define BIN_SHIFT 8
#define WINDOW    256
#define MAXBIN    512

typedef __attribute__((ext_vector_type(8))) short bf16x8;
typedef __attribute__((ext_vector_type(4))) float f32x4;

__device__ __forceinline__ short f2bf(float f) {
    __hip_bfloat16 h = __float2bfloat16(f);
    return *reinterpret_cast<short*>(&h);
}
__device__ __forceinline__ float bf_lo(unsigned int v) {
    union { unsigned int u; float f; } x; x.u = v << 16; return x.f;
}

// ---------------------------------------------------------------------------
// prep (grid 130):
//  blocks 0..127 : cond projection output o (weight-normed) -> gamma/beta
//  block 128     : weight-norm lin_w_v rows -> wlin_bf [128 o][64 k] bf16
//  block 129     : film_w -> fw_bf [64 h][256 k] bf16 ; zero bin_cnt
// ---------------------------------------------------------------------------
__global__ __launch_bounds__(256) void prep(
    const float* __restrict__ cond_feats,
    const float* __restrict__ cond_w_v,
    const float* __restrict__ cond_w_g,
    const float* __restrict__ cond_b,
    const float* __restrict__ lin_w_v,
    const float* __restrict__ lin_w_g,
    const float* __restrict__ film_w,
    float* __restrict__ gamma, float* __restrict__ beta,
    short* __restrict__ wlin_bf, short* __restrict__ fw_bf,
    int* __restrict__ bin_cnt, int nbin, int N, int B)
{
    const int t = threadIdx.x;
    const int bid = blockIdx.x;
    if (bid == 128) {
        if (t < OUT_DIM) {
            const int o = t;
            float nrm = 0.f;
            float w[HID];
            #pragma unroll
            for (int k = 0; k < HID; ++k) {
                w[k] = lin_w_v[o * HID + k];
                nrm += w[k] * w[k];
            }
            const float s = lin_w_g[o] * rsqrtf(nrm);
            #pragma unroll
            for (int k = 0; k < HID; ++k) wlin_bf[o * HID + k] = f2bf(w[k] * s);
        }
        return;
    }
    if (bid == 129) {
        if (t < nbin) bin_cnt[t] = 0;
        if (t + 256 < nbin) bin_cnt[t + 256] = 0;
        for (int idx = t; idx < HID * NODE_DIM; idx += 256)
            fw_bf[idx] = f2bf(film_w[idx]);
        return;
    }
    const int o = bid;
    const int lane = t & 63;
    const int wv = t >> 6;
    __shared__ float s_cp[64];
    __shared__ float s_nrm;
    float wreg[COND_DIM / 64];
    #pragma unroll
    for (int j = 0; j < COND_DIM / 64; ++j)
        wreg[j] = cond_w_v[o * COND_DIM + j * 64 + lane];
    float nr = 0.f;
    #pragma unroll
    for (int j = 0; j < COND_DIM / 64; ++j) nr += wreg[j] * wreg[j];
    #pragma unroll
    for (int off = 32; off > 0; off >>= 1) nr += __shfl_xor(nr, off, 64);
    if (t == 0) s_nrm = nr;
    for (int b = wv; b < 64; b += 4) {
        float a = 0.f;
        #pragma unroll
        for (int j = 0; j < COND_DIM / 64; ++j)
            a += wreg[j] * cond_feats[b * COND_DIM + j * 64 + lane];
        #pragma unroll
        for (int off = 32; off > 0; off >>= 1) a += __shfl_xor(a, off, 64);
        if (lane == 0) s_cp[b] = a;
    }
    __syncthreads();
    if (t < 64) {
        const float scale = cond_w_g[o] * rsqrtf(s_nrm);
        const float cp = scale * s_cp[t] + cond_b[o];
        if (o < HID) gamma[t * HID + o] = cp + 1.0f;
        else         beta[t * HID + (o - HID)] = cp;
    }
}

// ---------------------------------------------------------------------------
// fused_phase1: film path + dst-bin counting.
// NEW: the 64x256 A-tile is staged through LDS. Global reads are now fully
// SEQUENTIAL (each wave streams contiguous 2KB chunks) instead of the MFMA
// fragment pattern (16 rows x 128B at 1KB stride) that fragmented every
// vector load into 16 scattered segments and capped the kernel at ~1.4TB/s.
// LDS layout is chunk-XOR-swizzled so fragment ds_read_b128 is 2-way max
// (free).
// ---------------------------------------------------------------------------
__global__ __launch_bounds__(256) void fused_phase1(
    const float* __restrict__ nf,
    const short* __restrict__ fw_bf,      // [64 h][256 k]
    const float* __restrict__ film_b,
    const float* __restrict__ gamma, const float* __restrict__ beta,
    const int*  __restrict__ n2g,
    unsigned short* __restrict__ h_out,   // [N][64] bf16
    const int* __restrict__ ei,
    int* __restrict__ bin_cnt,
    int N, int E, int nbin)
{
    __shared__ int hist[MAXBIN];
    __shared__ unsigned short As[64 * 256];   // 32 KB bf16, swizzled chunks
    const int t = threadIdx.x;
    const int bid = blockIdx.x;
    const int n0 = bid * 64;

    hist[t] = 0; hist[t + 256] = 0;

    // ---- stage A tile: sequential global reads -> swizzled LDS ----------
    {
        const int jj = t & 31;            // logical 16B chunk within row
        const int rbase = t >> 5;         // 0..7
        const int p = jj ^ ((rbase & 7) << 2);   // physical chunk (const per thread)
        #pragma unroll 4
        for (int i = 0; i < 8; ++i) {
            const int r = i * 8 + rbase;  // r&7 == rbase&7
            const int node = n0 + r;
            const size_t ga = (size_t)((node < N) ? node : (N - 1)) * NODE_DIM + jj * 8;
            const float4 a0 = *(const float4*)(nf + ga);
            const float4 a1 = *(const float4*)(nf + ga + 4);
            bf16x8 v;
            v[0]=f2bf(a0.x); v[1]=f2bf(a0.y); v[2]=f2bf(a0.z); v[3]=f2bf(a0.w);
            v[4]=f2bf(a1.x); v[5]=f2bf(a1.y); v[6]=f2bf(a1.z); v[7]=f2bf(a1.w);
            *(bf16x8*)(As + r * 256 + p * 8) = v;
        }
    }
    __syncthreads();   // hist zeroed + A staged

    // ---- bin count: 1024 edges per block --------------------------------
    {
        const int e0 = bid * 1024 + t * 4;
        if (e0 + 3 < E) {
            const int4 d4 = *(const int4*)(ei + E + e0);
            atomicAdd(&hist[d4.x >> BIN_SHIFT], 1);
            atomicAdd(&hist[d4.y >> BIN_SHIFT], 1);
            atomicAdd(&hist[d4.z >> BIN_SHIFT], 1);
            atomicAdd(&hist[d4.w >> BIN_SHIFT], 1);
        } else {
            for (int j = 0; j < 4; ++j) {
                const int e = e0 + j;
                if (e < E) atomicAdd(&hist[ei[E + e] >> BIN_SHIFT], 1);
            }
        }
    }
    __syncthreads();
    if (hist[t] > 0) atomicAdd(&bin_cnt[t], hist[t]);                    // no-return
    if (t + 256 < nbin && hist[t + 256] > 0) atomicAdd(&bin_cnt[t + 256], hist[t + 256]);

    // ---- film path (A from LDS) -----------------------------------------
    if (n0 >= N) return;
    const int w = t >> 6;
    const int lane = t & 63;
    const int c = lane & 15;
    const int quad = lane >> 4;
    const int r = w * 16 + c;
    const int swz = (r & 7) << 2;

    f32x4 c1[4];
    #pragma unroll
    for (int q = 0; q < 4; ++q) { c1[q][0]=0.f; c1[q][1]=0.f; c1[q][2]=0.f; c1[q][3]=0.f; }

    #pragma unroll
    for (int kt = 0; kt < 8; ++kt) {
        const int p = (kt * 4 + quad) ^ swz;
        const bf16x8 af = *(const bf16x8*)(As + r * 256 + p * 8);
        #pragma unroll
        for (int nt = 0; nt < 4; ++nt) {
            const bf16x8 bfr = *(const bf16x8*)(fw_bf + ((nt * 16 + c) * NODE_DIM + kt * 32 + quad * 8));
            c1[nt] = __builtin_amdgcn_mfma_f32_16x16x32_bf16(af, bfr, c1[nt], 0, 0, 0);
        }
    }

    #pragma unroll
    for (int nt = 0; nt < 4; ++nt) {
        const float b = film_b[nt * 16 + c];
        c1[nt][0] += b; c1[nt][1] += b; c1[nt][2] += b; c1[nt][3] += b;
    }

    float sum[4], sq[4];
    #pragma unroll
    for (int rr = 0; rr < 4; ++rr) {
        sum[rr] = c1[0][rr] + c1[1][rr] + c1[2][rr] + c1[3][rr];
        sq[rr]  = c1[0][rr]*c1[0][rr] + c1[1][rr]*c1[1][rr]
                + c1[2][rr]*c1[2][rr] + c1[3][rr]*c1[3][rr];
    }
    #pragma unroll
    for (int off = 1; off < 16; off <<= 1) {
        #pragma unroll
        for (int rr = 0; rr < 4; ++rr) {
            sum[rr] += __shfl_xor(sum[rr], off, 64);
            sq[rr]  += __shfl_xor(sq[rr],  off, 64);
        }
    }
    float mu[4], inv[4];
    int gid[4];
    #pragma unroll
    for (int rr = 0; rr < 4; ++rr) {
        mu[rr] = sum[rr] * (1.0f / HID);
        float var = sq[rr] * (1.0f / HID) - mu[rr] * mu[rr];
        var = fmaxf(var, 0.f);
        inv[rr] = rsqrtf(var + LN_EPS);
        const int nn = n0 + w * 16 + quad * 4 + rr;
        gid[rr] = n2g[(nn < N) ? nn : (N - 1)];
    }

    #pragma unroll
    for (int rr = 0; rr < 4; ++rr) {
        const int nn = n0 + w * 16 + quad * 4 + rr;
        if (nn >= N) continue;
        #pragma unroll
        for (int nt = 0; nt < 4; ++nt) {
            const int col = nt * 16 + c;
            const float ga = gamma[gid[rr] * HID + col];
            const float be = beta[gid[rr] * HID + col];
            const float v = fmaxf(ga * ((c1[nt][rr] - mu[rr]) * inv[rr]) + be, 0.f);
            h_out[(size_t)nn * HID + col] = (unsigned short)f2bf(v);
        }
    }
}

// ---------------------------------------------------------------------------
// bin_scan: one block, 512 threads. Exclusive scan of bin_cnt -> bin_off;
// bin_cur = bin_off.
// ---------------------------------------------------------------------------
__global__ __launch_bounds__(512) void bin_scan(
    const int* __restrict__ bin_cnt, int* __restrict__ bin_off,
    int* __restrict__ bin_cur, int nbin)
{
    __shared__ int sA[512], sB[512];
    const int t = threadIdx.x;
    sA[t] = (t < nbin) ? bin_cnt[t] : 0;
    __syncthreads();
    int* cur = sA; int* nxt = sB;
    for (int off = 1; off < 512; off <<= 1) {
        nxt[t] = cur[t] + ((t >= off) ? cur[t - off] : 0);
        __syncthreads();
        int* tmp = cur; cur = nxt; nxt = tmp;
    }
    if (t < nbin) {
        const int excl = cur[t] - bin_cnt[t];
        bin_off[t] = excl;
        bin_cur[t] = excl;
    }
}

// ---------------------------------------------------------------------------
// partition: 4096 edges/block. LDS hist -> one returning global atomic per
// (block,bin) chunk reservation -> scatter (src,dst) int2 into part[].
// ---------------------------------------------------------------------------
__global__ __launch_bounds__(256) void partition(
    const int* __restrict__ ei, int* __restrict__ bin_cur,
    int2* __restrict__ part, int E, int nbin)
{
    __shared__ int hist[MAXBIN];
    __shared__ int chunkbase[MAXBIN];
    __shared__ int cursor[MAXBIN];
    const int t = threadIdx.x;
    hist[t] = 0; hist[t + 256] = 0;
    cursor[t] = 0; cursor[t + 256] = 0;
    __syncthreads();
    const int base = blockIdx.x * 4096;

    #pragma unroll
    for (int j = 0; j < 4; ++j) {
        const int e0 = base + j * 1024 + t * 4;
        if (e0 + 3 < E) {
            const int4 d4 = *(const int4*)(ei + E + e0);
            atomicAdd(&hist[d4.x >> BIN_SHIFT], 1);
            atomicAdd(&hist[d4.y >> BIN_SHIFT], 1);
            atomicAdd(&hist[d4.z >> BIN_SHIFT], 1);
            atomicAdd(&hist[d4.w >> BIN_SHIFT], 1);
        } else {
            for (int k = 0; k < 4; ++k) {
                const int e = e0 + k;
                if (e < E) atomicAdd(&hist[ei[E + e] >> BIN_SHIFT], 1);
            }
        }
    }
    __syncthreads();
    {
        const int c0 = hist[t];
        chunkbase[t] = (c0 > 0) ? atomicAdd(&bin_cur[t], c0) : 0;
        if (t + 256 < nbin) {
            const int c1 = hist[t + 256];
            chunkbase[t + 256] = (c1 > 0) ? atomicAdd(&bin_cur[t + 256], c1) : 0;
        }
    }
    __syncthreads();

    #pragma unroll
    for (int j = 0; j < 4; ++j) {
        const int e0 = base + j * 1024 + t * 4;
        if (e0 + 3 < E) {
            const int4 d4 = *(const int4*)(ei + E + e0);
            const int4 s4 = *(const int4*)(ei + e0);
            int b, r;
            b = d4.x >> BIN_SHIFT; r = atomicAdd(&cursor[b], 1);
            part[chunkbase[b] + r] = make_int2(s4.x, d4.x);
            b = d4.y >> BIN_SHIFT; r = atomicAdd(&cursor[b], 1);
            part[chunkbase[b] + r] = make_int2(s4.y, d4.y);
            b = d4.z >> BIN_SHIFT; r = atomicAdd(&cursor[b], 1);
            part[chunkbase[b] + r] = make_int2(s4.z, d4.z);
            b = d4.w >> BIN_SHIFT; r = atomicAdd(&cursor[b], 1);
            part[chunkbase[b] + r] = make_int2(s4.w, d4.w);
        } else {
            for (int k = 0; k < 4; ++k) {
                const int e = e0 + k;
                if (e < E) {
                    const int d = ei[E + e];
                    const int b = d >> BIN_SHIFT;
                    const int r = atomicAdd(&cursor[b], 1);
                    part[chunkbase[b] + r] = make_int2(ei[e], d);
                }
            }
        }
    }
}

// ---------------------------------------------------------------------------
// bin_aggregate: one block per 256-node window. fp32 accumulator tile in LDS
// (64KB). Streams the bin's edges once: gather h[src] row (one wave-instr =
// one 128B row, lane = feat), ds_add_f32 into tile (64 consecutive words ->
// 2-way bank alias = free). Replaces bin_build + edge_aggregate_h: no CSR,
// no bucket_src, no 100K-node scan, no ragged-degree wasted lanes.
// Writes mean_bf (bf16 packed) + deg.
// ---------------------------------------------------------------------------
__global__ __launch_bounds__(512) void bin_aggregate(
    const int2* __restrict__ part, const int* __restrict__ bin_cnt,
    const int* __restrict__ bin_off,
    const unsigned short* __restrict__ h,   // [N][64] bf16
    unsigned int* __restrict__ mean_bf,     // [N][32] packed bf16 pairs
    int* __restrict__ deg, int N)
{
    __shared__ float acc[WINDOW * HID];     // 64 KB
    __shared__ int degl[WINDOW];
    const int b = blockIdx.x;
    const int t = threadIdx.x;
    const int base = bin_off[b];
    const int cnt  = bin_cnt[b];
    const int w0 = b << BIN_SHIFT;
    const int wsize = min(WINDOW, N - w0);

    {
        const float4 z = make_float4(0.f, 0.f, 0.f, 0.f);
        float4* a4 = (float4*)acc;
        #pragma unroll
        for (int i = 0; i < (WINDOW * HID / 4) / 512; ++i)
            a4[i * 512 + t] = z;
        if (t < WINDOW) degl[t] = 0;
    }
    __syncthreads();

    const int lane = t & 63;
    const int wv = t >> 6;   // 0..7

    // main accumulate: 8 edges per wave-iteration (8 gathers in flight)
    for (int i0 = wv * 8; i0 < cnt; i0 += 64) {
        int src[8], dl[8];
        #pragma unroll
        for (int j = 0; j < 8; ++j) {
            const int idx = i0 + j;
            const int2 e = part[base + ((idx < cnt) ? idx : 0)];
            src[j] = e.x;
            dl[j] = (idx < cnt) ? (e.y - w0) : -1;
        }
        unsigned short hv[8];
        #pragma unroll
        for (int j = 0; j < 8; ++j)
            hv[j] = h[(size_t)src[j] * HID + lane];
        #pragma unroll
        for (int j = 0; j < 8; ++j) {
            if (dl[j] >= 0)
                atomicAdd(&acc[dl[j] * HID + lane], bf_lo((unsigned int)hv[j]));
        }
    }
    // deg pass (part is L1/L2 hot from the main loop)
    for (int i = t; i < cnt; i += 512)
        atomicAdd(&degl[part[base + i].y - w0], 1);
    __syncthreads();

    // epilogue: mean (bf16 packed) + deg. Wave writes 2 rows x 128B contiguous.
    const int u = t & 31;
    for (int r = t >> 5; r < wsize; r += 16) {
        const float inv = 1.f / fmaxf((float)degl[r], 1.f);
        const float2 v = *(const float2*)&acc[r * HID + u * 2];
        const unsigned int pl = (unsigned short)f2bf(v.x * inv);
        const unsigned int ph = (unsigned short)f2bf(v.y * inv);
        mean_bf[(size_t)(w0 + r) * 32 + u] = pl | (ph << 16);
    }
    for (int i = t; i < wsize; i += 512) deg[w0 + i] = degl[i];
}

// ---------------------------------------------------------------------------
// final linear via MFMA: out = relu(mean_h @ wlinT + lin_b), 0 where deg==0.
// ---------------------------------------------------------------------------
__global__ __launch_bounds__(256) void final_linear(
    const short* __restrict__ mean_bf,    // [N][64] bf16
    const short* __restrict__ wlin_bf,    // [128 o][64 k]
    const float* __restrict__ lin_b,
    const int*  __restrict__ deg,
    float* __restrict__ out, int N)
{
    const int tid = threadIdx.x;
    const int w = tid >> 6;
    const int lane = tid & 63;
    const int c = lane & 15;
    const int quad = lane >> 4;
    const int n0 = blockIdx.x * 64;

    const int mnode = n0 + w * 16 + c;
    const int arow = (mnode < N) ? mnode : (N - 1);
    const short* aptr = mean_bf + (size_t)arow * HID + quad * 8;

    f32x4 c2[8];
    #pragma unroll
    for (int q = 0; q < 8; ++q) { c2[q][0]=0.f; c2[q][1]=0.f; c2[q][2]=0.f; c2[q][3]=0.f; }

    #pragma unroll
    for (int kt = 0; kt < 2; ++kt) {
        const bf16x8 af = *(const bf16x8*)(aptr + kt * 32);
        #pragma unroll
        for (int nt = 0; nt < 8; ++nt) {
            const bf16x8 bfr = *(const bf16x8*)(wlin_bf + (nt * 16 + c) * HID + kt * 32 + quad * 8);
            c2[nt] = __builtin_amdgcn_mfma_f32_16x16x32_bf16(af, bfr, c2[nt], 0, 0, 0);
        }
    }

    float mask[4];
    #pragma unroll
    for (int r = 0; r < 4; ++r) {
        const int nn = n0 + w * 16 + quad * 4 + r;
        const int nc = (nn < N) ? nn : (N - 1);
        mask[r] = (deg[nc] > 0) ? 1.f : 0.f;
    }

    #pragma unroll
    for (int nt = 0; nt < 8; ++nt) {
        const float lb = lin_b[nt * 16 + c];
        #pragma unroll
        for (int r = 0; r < 4; ++r) {
            const int nn = n0 + w * 16 + quad * 4 + r;
            if (nn < N)
                out[(size_t)nn * OUT_DIM + nt * 16 + c] =
                    mask[r] * fmaxf(c2[nt][r] + lb, 0.f);
        }
    }
}

extern "C" void kernel_launch(void* const* d_in, const int* in_sizes, int n_in,
                              void* d_out, int out_size, void* d_ws, size_t ws_size,
                              hipStream_t stream) {
    const float* node_feats = (const float*)d_in[0];
    const float* cond_feats = (const float*)d_in[1];
    const float* cond_w_v   = (const float*)d_in[2];
    const float* cond_w_g   = (const float*)d_in[3];
    const float* cond_b     = (const float*)d_in[4];
    const float* film_w     = (const float*)d_in[5];
    const float* film_b     = (const float*)d_in[6];
    const float* lin_w_v    = (const float*)d_in[7];
    const float* lin_w_g    = (const float*)d_in[8];
    const float* lin_b      = (const float*)d_in[9];
    const int* edge_index   = (const int*)d_in[10];
    const int* node2graph   = (const int*)d_in[11];

    const int N = in_sizes[0] / NODE_DIM;     // 100000
    const int B = in_sizes[1] / COND_DIM;     // 64
    const int E = in_sizes[10] / 2;           // 1600000
    const int nbin = (N + WINDOW - 1) >> BIN_SHIFT;   // 391

    auto align_up = [](size_t x) { return (x + 255) & ~(size_t)255; };
    char* ws = (char*)d_ws;
    size_t off = 0;
    int* deg        = (int*)(ws + off); off += align_up((size_t)N * 4);
    int* bin_cnt    = (int*)(ws + off); off += align_up(MAXBIN * 4);
    int* bin_off    = (int*)(ws + off); off += align_up(MAXBIN * 4);
    int* bin_cur    = (int*)(ws + off); off += align_up(MAXBIN * 4);
    int2* part      = (int2*)(ws + off); off += align_up((size_t)E * 8);
    unsigned short* h_buf = (unsigned short*)(ws + off); off += align_up((size_t)N * HID * 2);
    unsigned int* mean_bf = (unsigned int*)(ws + off); off += align_up((size_t)N * HID * 2);
    float* gamma    = (float*)(ws + off); off += align_up((size_t)B * HID * 4);
    float* beta     = (float*)(ws + off); off += align_up((size_t)B * HID * 4);
    short* wlin_bf  = (short*)(ws + off); off += align_up((size_t)OUT_DIM * HID * 2);
    short* fw_bf    = (short*)(ws + off); off += align_up((size_t)HID * NODE_DIM * 2);

    prep<<<130, 256, 0, stream>>>(cond_feats, cond_w_v, cond_w_g, cond_b,
                                  lin_w_v, lin_w_g, film_w,
                                  gamma, beta, wlin_bf, fw_bf, bin_cnt, nbin, N, B);

    const int G_film = (N + 63) / 64;                 // 1563
    const int G_edge = (E + 1023) / 1024;             // 1563
    const int G1 = (G_film > G_edge) ? G_film : G_edge;
    fused_phase1<<<G1, 256, 0, stream>>>(
        node_feats, fw_bf, film_b, gamma, beta, node2graph, h_buf,
        edge_index, bin_cnt, N, E, nbin);

    bin_scan<<<1, 512, 0, stream>>>(bin_cnt, bin_off, bin_cur, nbin);

    partition<<<(E + 4095) / 4096, 256, 0, stream>>>(edge_index, bin_cur, part, E, nbin);

    bin_aggregate<<<nbin, 512, 0, stream>>>(part, bin_cnt, bin_off,
                                            h_buf, mean_bf, deg, N);

    final_linear<<<(N + 63) / 64, 256, 0, stream>>>(
        (const short*)mean_bf, wlin_bf, lin_b, deg, (float*)d_out, N);
}

// Round 4
// 350.688 us; speedup vs baseline: 2.7804x; 2.7804x over previous
//
#include <hip/hip_runtime.h>
#include <hip/hip_bf16.h>

#define NODE_DIM 256
#define COND_DIM 512
#define OUT_DIM  128
#define HID      64
#define LN_EPS   1e-5f

// dst-bin partition: bins of 512 nodes -> nbin = ceil(N/512) (=196 for N=100000)
#define BIN_SHIFT 9
#define WINDOW    512
#define MAXBIN    256

typedef __attribute__((ext_vector_type(8))) short bf16x8;
typedef __attribute__((ext_vector_type(4))) float f32x4;

__device__ __forceinline__ short f2bf(float f) {
    __hip_bfloat16 h = __float2bfloat16(f);
    return *reinterpret_cast<short*>(&h);
}
__device__ __forceinline__ float bf_lo(unsigned int v) {
    union { unsigned int u; float f; } x; x.u = v << 16; return x.f;
}
__device__ __forceinline__ float bf_hi(unsigned int v) {
    union { unsigned int u; float f; } x; x.u = v & 0xffff0000u; return x.f;
}

// ---------------------------------------------------------------------------
// prep (grid 130):
//  blocks 0..127 : cond projection output o (weight-normed) -> gamma/beta
//  block 128     : weight-norm lin_w_v rows -> wlin_bf [128 o][64 k] bf16
//  block 129     : film_w -> fw_bf [64 h][256 k] bf16 ; zero bin_cnt
// ---------------------------------------------------------------------------
__global__ __launch_bounds__(256) void prep(
    const float* __restrict__ cond_feats,
    const float* __restrict__ cond_w_v,
    const float* __restrict__ cond_w_g,
    const float* __restrict__ cond_b,
    const float* __restrict__ lin_w_v,
    const float* __restrict__ lin_w_g,
    const float* __restrict__ film_w,
    float* __restrict__ gamma, float* __restrict__ beta,
    short* __restrict__ wlin_bf, short* __restrict__ fw_bf,
    int* __restrict__ bin_cnt, int nbin, int N, int B)
{
    const int t = threadIdx.x;
    const int bid = blockIdx.x;
    if (bid == 128) {
        if (t < OUT_DIM) {
            const int o = t;
            float nrm = 0.f;
            float w[HID];
            #pragma unroll
            for (int k = 0; k < HID; ++k) {
                w[k] = lin_w_v[o * HID + k];
                nrm += w[k] * w[k];
            }
            const float s = lin_w_g[o] * rsqrtf(nrm);
            #pragma unroll
            for (int k = 0; k < HID; ++k) wlin_bf[o * HID + k] = f2bf(w[k] * s);
        }
        return;
    }
    if (bid == 129) {
        if (t < nbin) bin_cnt[t] = 0;
        for (int idx = t; idx < HID * NODE_DIM; idx += 256)
            fw_bf[idx] = f2bf(film_w[idx]);
        return;
    }
    const int o = bid;
    const int lane = t & 63;
    const int wv = t >> 6;
    __shared__ float s_cp[64];
    __shared__ float s_nrm;
    float wreg[COND_DIM / 64];
    #pragma unroll
    for (int j = 0; j < COND_DIM / 64; ++j)
        wreg[j] = cond_w_v[o * COND_DIM + j * 64 + lane];
    float nr = 0.f;
    #pragma unroll
    for (int j = 0; j < COND_DIM / 64; ++j) nr += wreg[j] * wreg[j];
    #pragma unroll
    for (int off = 32; off > 0; off >>= 1) nr += __shfl_xor(nr, off, 64);
    if (t == 0) s_nrm = nr;
    for (int b = wv; b < 64; b += 4) {
        float a = 0.f;
        #pragma unroll
        for (int j = 0; j < COND_DIM / 64; ++j)
            a += wreg[j] * cond_feats[b * COND_DIM + j * 64 + lane];
        #pragma unroll
        for (int off = 32; off > 0; off >>= 1) a += __shfl_xor(a, off, 64);
        if (lane == 0) s_cp[b] = a;
    }
    __syncthreads();
    if (t < 64) {
        const float scale = cond_w_g[o] * rsqrtf(s_nrm);
        const float cp = scale * s_cp[t] + cond_b[o];
        if (o < HID) gamma[t * HID + o] = cp + 1.0f;
        else         beta[t * HID + (o - HID)] = cp;
    }
}

// ---------------------------------------------------------------------------
// fused_phase1: film path + dst-bin counting (int LDS hist, no-return global
// adds). A-tile staged through LDS: sequential global reads (each wave
// streams contiguous chunks) instead of the MFMA fragment pattern
// (16 rows x 128B @ 1KB stride) that fragmented every vector load.
// ---------------------------------------------------------------------------
__global__ __launch_bounds__(256) void fused_phase1(
    const float* __restrict__ nf,
    const short* __restrict__ fw_bf,      // [64 h][256 k]
    const float* __restrict__ film_b,
    const float* __restrict__ gamma, const float* __restrict__ beta,
    const int*  __restrict__ n2g,
    unsigned short* __restrict__ h_out,   // [N][64] bf16
    const int* __restrict__ ei,
    int* __restrict__ bin_cnt,
    int N, int E, int nbin)
{
    __shared__ int hist[MAXBIN];
    __shared__ unsigned short As[64 * 256];   // 32 KB bf16, swizzled chunks
    const int t = threadIdx.x;
    const int bid = blockIdx.x;
    const int n0 = bid * 64;

    hist[t] = 0;

    // ---- stage A tile: sequential global reads -> swizzled LDS ----------
    {
        const int jj = t & 31;            // logical 16B chunk within row
        const int rbase = t >> 5;         // 0..7
        const int p = jj ^ ((rbase & 7) << 2);   // physical chunk (const per thread)
        #pragma unroll 4
        for (int i = 0; i < 8; ++i) {
            const int r = i * 8 + rbase;  // r&7 == rbase&7
            const int node = n0 + r;
            const size_t ga = (size_t)((node < N) ? node : (N - 1)) * NODE_DIM + jj * 8;
            const float4 a0 = *(const float4*)(nf + ga);
            const float4 a1 = *(const float4*)(nf + ga + 4);
            bf16x8 v;
            v[0]=f2bf(a0.x); v[1]=f2bf(a0.y); v[2]=f2bf(a0.z); v[3]=f2bf(a0.w);
            v[4]=f2bf(a1.x); v[5]=f2bf(a1.y); v[6]=f2bf(a1.z); v[7]=f2bf(a1.w);
            *(bf16x8*)(As + r * 256 + p * 8) = v;
        }
    }
    __syncthreads();   // hist zeroed + A staged

    // ---- bin count: 1024 edges per block --------------------------------
    {
        const int e0 = bid * 1024 + t * 4;
        if (e0 + 3 < E) {
            const int4 d4 = *(const int4*)(ei + E + e0);
            atomicAdd(&hist[d4.x >> BIN_SHIFT], 1);
            atomicAdd(&hist[d4.y >> BIN_SHIFT], 1);
            atomicAdd(&hist[d4.z >> BIN_SHIFT], 1);
            atomicAdd(&hist[d4.w >> BIN_SHIFT], 1);
        } else {
            for (int j = 0; j < 4; ++j) {
                const int e = e0 + j;
                if (e < E) atomicAdd(&hist[ei[E + e] >> BIN_SHIFT], 1);
            }
        }
    }
    __syncthreads();
    if (t < nbin && hist[t] > 0) atomicAdd(&bin_cnt[t], hist[t]);  // no-return

    // ---- film path (A from LDS) -----------------------------------------
    if (n0 >= N) return;
    const int w = t >> 6;
    const int lane = t & 63;
    const int c = lane & 15;
    const int quad = lane >> 4;
    const int r = w * 16 + c;
    const int swz = (r & 7) << 2;

    f32x4 c1[4];
    #pragma unroll
    for (int q = 0; q < 4; ++q) { c1[q][0]=0.f; c1[q][1]=0.f; c1[q][2]=0.f; c1[q][3]=0.f; }

    #pragma unroll
    for (int kt = 0; kt < 8; ++kt) {
        const int p = (kt * 4 + quad) ^ swz;
        const bf16x8 af = *(const bf16x8*)(As + r * 256 + p * 8);
        #pragma unroll
        for (int nt = 0; nt < 4; ++nt) {
            const bf16x8 bfr = *(const bf16x8*)(fw_bf + ((nt * 16 + c) * NODE_DIM + kt * 32 + quad * 8));
            c1[nt] = __builtin_amdgcn_mfma_f32_16x16x32_bf16(af, bfr, c1[nt], 0, 0, 0);
        }
    }

    #pragma unroll
    for (int nt = 0; nt < 4; ++nt) {
        const float b = film_b[nt * 16 + c];
        c1[nt][0] += b; c1[nt][1] += b; c1[nt][2] += b; c1[nt][3] += b;
    }

    float sum[4], sq[4];
    #pragma unroll
    for (int rr = 0; rr < 4; ++rr) {
        sum[rr] = c1[0][rr] + c1[1][rr] + c1[2][rr] + c1[3][rr];
        sq[rr]  = c1[0][rr]*c1[0][rr] + c1[1][rr]*c1[1][rr]
                + c1[2][rr]*c1[2][rr] + c1[3][rr]*c1[3][rr];
    }
    #pragma unroll
    for (int off = 1; off < 16; off <<= 1) {
        #pragma unroll
        for (int rr = 0; rr < 4; ++rr) {
            sum[rr] += __shfl_xor(sum[rr], off, 64);
            sq[rr]  += __shfl_xor(sq[rr],  off, 64);
        }
    }
    float mu[4], inv[4];
    int gid[4];
    #pragma unroll
    for (int rr = 0; rr < 4; ++rr) {
        mu[rr] = sum[rr] * (1.0f / HID);
        float var = sq[rr] * (1.0f / HID) - mu[rr] * mu[rr];
        var = fmaxf(var, 0.f);
        inv[rr] = rsqrtf(var + LN_EPS);
        const int nn = n0 + w * 16 + quad * 4 + rr;
        gid[rr] = n2g[(nn < N) ? nn : (N - 1)];
    }

    #pragma unroll
    for (int rr = 0; rr < 4; ++rr) {
        const int nn = n0 + w * 16 + quad * 4 + rr;
        if (nn >= N) continue;
        #pragma unroll
        for (int nt = 0; nt < 4; ++nt) {
            const int col = nt * 16 + c;
            const float ga = gamma[gid[rr] * HID + col];
            const float be = beta[gid[rr] * HID + col];
            const float v = fmaxf(ga * ((c1[nt][rr] - mu[rr]) * inv[rr]) + be, 0.f);
            h_out[(size_t)nn * HID + col] = (unsigned short)f2bf(v);
        }
    }
}

// ---------------------------------------------------------------------------
// bin_scan: one block. Exclusive scan of bin_cnt -> bin_off; bin_cur=bin_off;
// csr_off[N]=E.
// ---------------------------------------------------------------------------
__global__ __launch_bounds__(256) void bin_scan(
    const int* __restrict__ bin_cnt, int* __restrict__ bin_off,
    int* __restrict__ bin_cur, int* __restrict__ csr_off,
    int nbin, int N, int E)
{
    __shared__ int sA[256], sB[256];
    const int t = threadIdx.x;
    sA[t] = (t < nbin) ? bin_cnt[t] : 0;
    __syncthreads();
    int* cur = sA; int* nxt = sB;
    for (int off = 1; off < 256; off <<= 1) {
        nxt[t] = cur[t] + ((t >= off) ? cur[t - off] : 0);
        __syncthreads();
        int* tmp = cur; cur = nxt; nxt = tmp;
    }
    if (t < nbin) {
        const int excl = cur[t] - bin_cnt[t];
        bin_off[t] = excl;
        bin_cur[t] = excl;
    }
    if (t == 0) csr_off[N] = E;
}

// ---------------------------------------------------------------------------
// partition: 4096 edges/block. LDS hist (int atomics) -> one returning
// global atomic per (block,bin) -> scatter (src,dst) int2 into part[].
// ---------------------------------------------------------------------------
__global__ __launch_bounds__(256) void partition(
    const int* __restrict__ ei, int* __restrict__ bin_cur,
    int2* __restrict__ part, int E, int nbin)
{
    __shared__ int hist[MAXBIN];
    __shared__ int chunkbase[MAXBIN];
    __shared__ int cursor[MAXBIN];
    const int t = threadIdx.x;
    hist[t] = 0; cursor[t] = 0;
    __syncthreads();
    const int base = blockIdx.x * 4096;

    #pragma unroll
    for (int j = 0; j < 4; ++j) {
        const int e0 = base + j * 1024 + t * 4;
        if (e0 + 3 < E) {
            const int4 d4 = *(const int4*)(ei + E + e0);
            atomicAdd(&hist[d4.x >> BIN_SHIFT], 1);
            atomicAdd(&hist[d4.y >> BIN_SHIFT], 1);
            atomicAdd(&hist[d4.z >> BIN_SHIFT], 1);
            atomicAdd(&hist[d4.w >> BIN_SHIFT], 1);
        } else {
            for (int k = 0; k < 4; ++k) {
                const int e = e0 + k;
                if (e < E) atomicAdd(&hist[ei[E + e] >> BIN_SHIFT], 1);
            }
        }
    }
    __syncthreads();
    if (t < nbin) {
        const int cN = hist[t];
        chunkbase[t] = (cN > 0) ? atomicAdd(&bin_cur[t], cN) : 0;
    }
    __syncthreads();

    #pragma unroll
    for (int j = 0; j < 4; ++j) {
        const int e0 = base + j * 1024 + t * 4;
        if (e0 + 3 < E) {
            const int4 d4 = *(const int4*)(ei + E + e0);
            const int4 s4 = *(const int4*)(ei + e0);
            int b, r;
            b = d4.x >> BIN_SHIFT; r = atomicAdd(&cursor[b], 1);
            part[chunkbase[b] + r] = make_int2(s4.x, d4.x);
            b = d4.y >> BIN_SHIFT; r = atomicAdd(&cursor[b], 1);
            part[chunkbase[b] + r] = make_int2(s4.y, d4.y);
            b = d4.z >> BIN_SHIFT; r = atomicAdd(&cursor[b], 1);
            part[chunkbase[b] + r] = make_int2(s4.z, d4.z);
            b = d4.w >> BIN_SHIFT; r = atomicAdd(&cursor[b], 1);
            part[chunkbase[b] + r] = make_int2(s4.w, d4.w);
        } else {
            for (int k = 0; k < 4; ++k) {
                const int e = e0 + k;
                if (e < E) {
                    const int d = ei[E + e];
                    const int b = d >> BIN_SHIFT;
                    const int r = atomicAdd(&cursor[b], 1);
                    part[chunkbase[b] + r] = make_int2(ei[e], d);
                }
            }
        }
    }
}

// ---------------------------------------------------------------------------
// bin_build: one block per bin (512-node window). LDS hist over window ->
// csr_off written DIRECTLY (bin base + local exclusive scan), then
// counting-sort srcs into bucket_src. All-int LDS atomics (native ds_add).
// ---------------------------------------------------------------------------
__global__ __launch_bounds__(256) void bin_build(
    const int2* __restrict__ part, const int* __restrict__ bin_cnt,
    const int* __restrict__ bin_off, int* __restrict__ csr_off,
    int* __restrict__ bucket_src, int N)
{
    __shared__ int hist[WINDOW];
    __shared__ int sA[WINDOW], sB[WINDOW];
    __shared__ int cursor[WINDOW];
    const int b = blockIdx.x;
    const int t = threadIdx.x;
    const int base = bin_off[b];
    const int cnt  = bin_cnt[b];
    const int w0 = b << BIN_SHIFT;
    const int wsize = min(WINDOW, N - w0);

    hist[t] = 0; hist[t + 256] = 0;
    cursor[t] = 0; cursor[t + 256] = 0;
    __syncthreads();

    for (int i = t; i < cnt; i += 256)
        atomicAdd(&hist[part[base + i].y - w0], 1);
    __syncthreads();

    sA[t] = hist[t]; sA[t + 256] = hist[t + 256];
    __syncthreads();
    int* cur = sA; int* nxt = sB;
    for (int off = 1; off < WINDOW; off <<= 1) {
        nxt[t]       = cur[t]       + ((t       >= off) ? cur[t - off]       : 0);
        nxt[t + 256] = cur[t + 256] + ((t + 256 >= off) ? cur[t + 256 - off] : 0);
        __syncthreads();
        int* tmp = cur; cur = nxt; nxt = tmp;
    }
    // cur = inclusive scan; exclusive = cur[i] - hist[i]
    if (t < wsize)       csr_off[w0 + t]       = base + cur[t]       - hist[t];
    if (t + 256 < wsize) csr_off[w0 + t + 256] = base + cur[t + 256] - hist[t + 256];

    for (int i = t; i < cnt; i += 256) {
        const int2 e = part[base + i];
        const int ld = e.y - w0;
        const int r = atomicAdd(&cursor[ld], 1);
        bucket_src[base + (cur[ld] - hist[ld]) + r] = e.x;
    }
}

// ---------------------------------------------------------------------------
// gather-reduce over h rows (128 B = exactly 1 L2 line, fully used).
// ---------------------------------------------------------------------------
__global__ __launch_bounds__(256) void edge_aggregate_h(
    const int* __restrict__ csr_off, const int* __restrict__ bucket_src,
    const unsigned int* __restrict__ h,   // [N][32] uints
    unsigned int* __restrict__ mean_bf,   // [N][32] uints (bf16 pairs)
    int N)
{
    const int lane = threadIdx.x & 63;
    const int u = lane & 31;
    const int eo = lane >> 5;
    const int d0 = blockIdx.x * 32 + (threadIdx.x >> 6) * 8;

    #pragma unroll 1
    for (int i = 0; i < 8; ++i) {
        const int dst = d0 + i;
        if (dst >= N) return;
        const int base = csr_off[dst];
        const int end  = csr_off[dst + 1];
        float a0 = 0.f, a1 = 0.f;
        for (int p = base; p < end; p += 8) {
            const int e0 = p + eo;
            const int e1 = e0 + 2;
            const int e2 = e0 + 4;
            const int e3 = e0 + 6;
            const int s0 = bucket_src[(e0 < end) ? e0 : (end - 1)];
            const int s1 = bucket_src[(e1 < end) ? e1 : (end - 1)];
            const int s2 = bucket_src[(e2 < end) ? e2 : (end - 1)];
            const int s3 = bucket_src[(e3 < end) ? e3 : (end - 1)];
            const unsigned int v0 = h[(size_t)s0 * 32 + u];
            const unsigned int v1 = h[(size_t)s1 * 32 + u];
            const unsigned int v2 = h[(size_t)s2 * 32 + u];
            const unsigned int v3 = h[(size_t)s3 * 32 + u];
            const float m0 = (e0 < end) ? 1.f : 0.f;
            const float m1 = (e1 < end) ? 1.f : 0.f;
            const float m2 = (e2 < end) ? 1.f : 0.f;
            const float m3 = (e3 < end) ? 1.f : 0.f;
            a0 += m0 * bf_lo(v0) + m1 * bf_lo(v1) + m2 * bf_lo(v2) + m3 * bf_lo(v3);
            a1 += m0 * bf_hi(v0) + m1 * bf_hi(v1) + m2 * bf_hi(v2) + m3 * bf_hi(v3);
        }
        a0 += __shfl_xor(a0, 32, 64);
        a1 += __shfl_xor(a1, 32, 64);
        if (lane < 32) {
            const float d = fmaxf((float)(end - base), 1.f);
            const unsigned int lo = (unsigned short)f2bf(a0 / d);
            const unsigned int hi = (unsigned short)f2bf(a1 / d);
            mean_bf[(size_t)dst * 32 + u] = lo | (hi << 16);
        }
    }
}

// ---------------------------------------------------------------------------
// final linear via MFMA: out = relu(mean_h @ wlinT + lin_b), 0 where deg==0.
// ---------------------------------------------------------------------------
__global__ __launch_bounds__(256) void final_linear(
    const short* __restrict__ mean_bf,    // [N][64] bf16
    const short* __restrict__ wlin_bf,    // [128 o][64 k]
    const float* __restrict__ lin_b,
    const int*  __restrict__ csr_off,
    float* __restrict__ out, int N)
{
    const int tid = threadIdx.x;
    const int w = tid >> 6;
    const int lane = tid & 63;
    const int c = lane & 15;
    const int quad = lane >> 4;
    const int n0 = blockIdx.x * 64;

    const int mnode = n0 + w * 16 + c;
    const int arow = (mnode < N) ? mnode : (N - 1);
    const short* aptr = mean_bf + (size_t)arow * HID + quad * 8;

    f32x4 c2[8];
    #pragma unroll
    for (int q = 0; q < 8; ++q) { c2[q][0]=0.f; c2[q][1]=0.f; c2[q][2]=0.f; c2[q][3]=0.f; }

    #pragma unroll
    for (int kt = 0; kt < 2; ++kt) {
        const bf16x8 af = *(const bf16x8*)(aptr + kt * 32);
        #pragma unroll
        for (int nt = 0; nt < 8; ++nt) {
            const bf16x8 bfr = *(const bf16x8*)(wlin_bf + (nt * 16 + c) * HID + kt * 32 + quad * 8);
            c2[nt] = __builtin_amdgcn_mfma_f32_16x16x32_bf16(af, bfr, c2[nt], 0, 0, 0);
        }
    }

    float mask[4];
    #pragma unroll
    for (int r = 0; r < 4; ++r) {
        const int nn = n0 + w * 16 + quad * 4 + r;
        const int nc = (nn < N) ? nn : (N - 1);
        mask[r] = (csr_off[nc + 1] - csr_off[nc] > 0) ? 1.f : 0.f;
    }

    #pragma unroll
    for (int nt = 0; nt < 8; ++nt) {
        const float lb = lin_b[nt * 16 + c];
        #pragma unroll
        for (int r = 0; r < 4; ++r) {
            const int nn = n0 + w * 16 + quad * 4 + r;
            if (nn < N)
                out[(size_t)nn * OUT_DIM + nt * 16 + c] =
                    mask[r] * fmaxf(c2[nt][r] + lb, 0.f);
        }
    }
}

extern "C" void kernel_launch(void* const* d_in, const int* in_sizes, int n_in,
                              void* d_out, int out_size, void* d_ws, size_t ws_size,
                              hipStream_t stream) {
    const float* node_feats = (const float*)d_in[0];
    const float* cond_feats = (const float*)d_in[1];
    const float* cond_w_v   = (const float*)d_in[2];
    const float* cond_w_g   = (const float*)d_in[3];
    const float* cond_b     = (const float*)d_in[4];
    const float* film_w     = (const float*)d_in[5];
    const float* film_b     = (const float*)d_in[6];
    const float* lin_w_v    = (const float*)d_in[7];
    const float* lin_w_g    = (const float*)d_in[8];
    const float* lin_b      = (const float*)d_in[9];
    const int* edge_index   = (const int*)d_in[10];
    const int* node2graph   = (const int*)d_in[11];

    const int N = in_sizes[0] / NODE_DIM;     // 100000
    const int B = in_sizes[1] / COND_DIM;     // 64
    const int E = in_sizes[10] / 2;           // 1600000
    const int nbin = (N + WINDOW - 1) >> BIN_SHIFT;   // 196

    auto align_up = [](size_t x) { return (x + 255) & ~(size_t)255; };
    char* ws = (char*)d_ws;
    size_t off = 0;
    int* csr_off    = (int*)(ws + off); off += align_up((size_t)(N + 1) * 4);
    int* bin_cnt    = (int*)(ws + off); off += align_up(MAXBIN * 4);
    int* bin_off    = (int*)(ws + off); off += align_up(MAXBIN * 4);
    int* bin_cur    = (int*)(ws + off); off += align_up(MAXBIN * 4);
    int2* part      = (int2*)(ws + off); off += align_up((size_t)E * 8);
    int* bucket_src = (int*)(ws + off); off += align_up((size_t)E * 4);
    unsigned short* h_buf = (unsigned short*)(ws + off); off += align_up((size_t)N * HID * 2);
    unsigned int* mean_bf = (unsigned int*)(ws + off); off += align_up((size_t)N * HID * 2);
    float* gamma    = (float*)(ws + off); off += align_up((size_t)B * HID * 4);
    float* beta     = (float*)(ws + off); off += align_up((size_t)B * HID * 4);
    short* wlin_bf  = (short*)(ws + off); off += align_up((size_t)OUT_DIM * HID * 2);
    short* fw_bf    = (short*)(ws + off); off += align_up((size_t)HID * NODE_DIM * 2);

    prep<<<130, 256, 0, stream>>>(cond_feats, cond_w_v, cond_w_g, cond_b,
                                  lin_w_v, lin_w_g, film_w,
                                  gamma, beta, wlin_bf, fw_bf, bin_cnt, nbin, N, B);

    const int G_film = (N + 63) / 64;                 // 1563
    const int G_edge = (E + 1023) / 1024;             // 1563
    const int G1 = (G_film > G_edge) ? G_film : G_edge;
    fused_phase1<<<G1, 256, 0, stream>>>(
        node_feats, fw_bf, film_b, gamma, beta, node2graph, h_buf,
        edge_index, bin_cnt, N, E, nbin);

    bin_scan<<<1, 256, 0, stream>>>(bin_cnt, bin_off, bin_cur, csr_off, nbin, N, E);

    partition<<<(E + 4095) / 4096, 256, 0, stream>>>(edge_index, bin_cur, part, E, nbin);

    bin_build<<<nbin, 256, 0, stream>>>(part, bin_cnt, bin_off, csr_off,
                                        bucket_src, N);

    edge_aggregate_h<<<(N + 31) / 32, 256, 0, stream>>>(
        csr_off, bucket_src, (const unsigned int*)h_buf, mean_bf, N);

    final_linear<<<(N + 63) / 64, 256, 0, stream>>>(
        (const short*)mean_bf, wlin_bf, lin_b, csr_off, (float*)d_out, N);
}